// Round 1
// baseline (15.268 us; speedup 1.0000x reference)
//
#include <hip/hip_runtime.h>

// STFT->iSTFT round trip with pinv-based synthesis kernel.
//
// Algebraic reduction (exact, not approximate):
//   inputs == out  (stack+concat is identity)
//   yfr = frames @ (weight^T @ inv_weight) ; weight = kernel*window,
//   inv_weight = pinv(kernel).T * window, and pinv(kernel)@kernel = I
//   (kernel is 514x512, full column rank) =>
//   yfr[b,t,k] = frames[b,t,k] * window[k]^2
//   overlap-add(yfr) == xp * coff  (identical index sets, term-by-term)
//   y = xp * coff/(coff+1e-8) ~= xp  (coff >= 1.25 on the kept slice)
//   y[:, PAD:-PAD] == x
//
// So the kernel is a pure copy: d_out <- d_in[0]. Memory-roofline:
// 33.55 MB read + 33.55 MB write ~= 10.6 us at 6.3 TB/s.

__global__ __launch_bounds__(256) void stft_identity_copy(
    const float4* __restrict__ in, float4* __restrict__ out, int n4) {
    int i = blockIdx.x * blockDim.x + threadIdx.x;
    if (i < n4) out[i] = in[i];
}

extern "C" void kernel_launch(void* const* d_in, const int* in_sizes, int n_in,
                              void* d_out, int out_size, void* d_ws, size_t ws_size,
                              hipStream_t stream) {
    const float4* x = (const float4*)d_in[0];  // (B=32, T=262144) f32, 16B-aligned
    float4* out = (float4*)d_out;              // same shape/dtype

    int n4 = out_size / 4;                     // 8,388,608 / 4 = 2,097,152 float4
    int block = 256;
    int grid = (n4 + block - 1) / block;       // 8192 blocks
    stft_identity_copy<<<grid, block, 0, stream>>>(x, out, n4);
}